// Round 3
// baseline (19.684 us; speedup 1.0000x reference)
//
#include <hip/hip_runtime.h>

// out[b] = sum_{distinct v in x[:,b]} W[v] + b_lut[0] + bias[0]
//   x: (200, 1024) int32 row-major, W: (100000,) f32, out: (1024,) f32
//
// R2 -> R3: coalesce the x gather. Block owns 16 consecutive columns;
// thread t = (rowGroup = t>>4, col = t&15), so a wave's 64 loads cover
// 4 rows x 16 consecutive columns = 4 fully-utilized 64B lines.
// Per-column dedup via private 512-slot LDS hash table.

#define VSIZE   100000
#define LENGTH  200
#define BATCH   1024
#define COLS    16              // columns per block
#define HBITS   9
#define HSIZE   (1 << HBITS)    // 512 slots/column, load factor 0.39
#define EMPTY   0xFFFFFFFFu     // tokens < 100000 never collide with sentinel

__global__ __launch_bounds__(256) void LR2_kernel(
    const int* __restrict__ x,
    const float* __restrict__ W,
    const float* __restrict__ b_lut,
    const float* __restrict__ bias,
    float* __restrict__ out)
{
    __shared__ unsigned ht[COLS][HSIZE];
    __shared__ float    partial[4][COLS];

    const int t   = threadIdx.x;
    const int col = t & (COLS - 1);
    const int rg  = t >> 4;                       // row group 0..15
    const int c   = blockIdx.x * COLS + col;

    // rows handled: rg, rg+16, ... ; 200 = 12*16 + 8 -> rg<8 gets 13 rows
    const int nrows = (rg < (LENGTH & (COLS - 1))) ? (LENGTH / COLS + 1)
                                                   : (LENGTH / COLS);

    // Preload tokens (independent, coalesced loads all in flight).
    unsigned toks[13];
    #pragma unroll
    for (int k = 0; k < 13; ++k)
        if (k < nrows)
            toks[k] = (unsigned)x[(rg + COLS * k) * BATCH + c];

    // Clear hash tables, vectorized (8192 words = 2048 uint4 / 256 threads).
    uint4* htv = (uint4*)&ht[0][0];
    #pragma unroll
    for (int i = t; i < COLS * HSIZE / 4; i += 256)
        htv[i] = make_uint4(EMPTY, EMPTY, EMPTY, EMPTY);
    __syncthreads();

    float contrib = 0.0f;
    for (int k = 0; k < nrows; ++k) {
        unsigned tok = toks[k];
        unsigned h = (tok * 2654435761u) >> (32 - HBITS);
        for (;;) {
            unsigned old = atomicCAS(&ht[col][h], EMPTY, tok);
            if (old == EMPTY) { contrib += W[tok]; break; }  // first occurrence
            if (old == tok) break;                           // duplicate
            h = (h + 1) & (HSIZE - 1);
        }
    }

    // Reduce over rowGroup: bits 4,5 of t within the wave, then 4 waves via LDS.
    contrib += __shfl_xor(contrib, 16, 64);
    contrib += __shfl_xor(contrib, 32, 64);
    const int wave = t >> 6;
    if ((t & 63) < COLS) partial[wave][col] = contrib;
    __syncthreads();

    if (t < COLS) {
        float s = partial[0][t] + partial[1][t] + partial[2][t] + partial[3][t];
        out[blockIdx.x * COLS + t] = s + b_lut[0] + bias[0];
    }
}

extern "C" void kernel_launch(void* const* d_in, const int* in_sizes, int n_in,
                              void* d_out, int out_size, void* d_ws, size_t ws_size,
                              hipStream_t stream) {
    const int*   x     = (const int*)d_in[0];
    const float* W     = (const float*)d_in[1];
    const float* b_lut = (const float*)d_in[2];
    const float* bias  = (const float*)d_in[3];
    float*       out   = (float*)d_out;

    LR2_kernel<<<BATCH / COLS, 256, 0, stream>>>(x, W, b_lut, bias, out);
}

// Round 4
// 9.572 us; speedup vs baseline: 2.0564x; 2.0564x over previous
//
#include <hip/hip_runtime.h>

// out[b] = sum_{distinct v in x[:,b]} W[v] + b_lut[0] + bias[0]
//   x: (200, 1024) int32, W: (100000,) f32, out: (1024,) f32
//
// R4 = R2 structure (1 block per column, 1 token per thread -- max TLP,
// shortest dependent chain) + speculative W[tok] prefetch so the scattered
// W gather overlaps the hash-table clear + CAS instead of serializing
// after it. R3's 16-col blocking regressed 2x (TLP collapse) -- reverted.

#define VSIZE     100000
#define LENGTH    200
#define BATCH     1024
#define HASH_SIZE 1024
#define EMPTY     0xFFFFFFFFu   // tokens < 100000 never collide with sentinel

__global__ __launch_bounds__(256) void LR2_kernel(
    const int* __restrict__ x,
    const float* __restrict__ W,
    const float* __restrict__ b_lut,
    const float* __restrict__ bias,
    float* __restrict__ out)
{
    __shared__ unsigned ht[HASH_SIZE];
    __shared__ float    wsum[4];

    const int b = blockIdx.x;
    const int t = threadIdx.x;

    // Issue the long-latency loads FIRST: token gather, then speculative
    // W[tok] (correct for duplicates too -- just possibly unused).
    unsigned tok = EMPTY;
    float    w   = 0.0f;
    if (t < LENGTH) {
        tok = (unsigned)x[t * BATCH + b];
        w   = W[tok];                      // overlaps clear + sync + CAS
    }
    const float tail = b_lut[0] + bias[0]; // uniform s_loads, issued early

    // Vectorized hash-table clear: 1024 words = 256 uint4, one per thread.
    ((uint4*)ht)[t] = make_uint4(EMPTY, EMPTY, EMPTY, EMPTY);
    __syncthreads();

    float contrib = 0.0f;
    if (t < LENGTH) {
        unsigned h = (tok * 2654435761u) >> 22;  // Knuth hash, top 10 bits
        for (;;) {
            unsigned old = atomicCAS(&ht[h], EMPTY, tok);
            if (old == EMPTY) { contrib = w; break; }  // first occurrence
            if (old == tok) break;                     // duplicate
            h = (h + 1) & (HASH_SIZE - 1);
        }
    }

    // Wave shuffle reduction, then 4 waves via LDS.
    for (int off = 32; off > 0; off >>= 1)
        contrib += __shfl_down(contrib, off, 64);

    const int wave = t >> 6;
    if ((t & 63) == 0) wsum[wave] = contrib;
    __syncthreads();

    if (t == 0)
        out[b] = wsum[0] + wsum[1] + wsum[2] + wsum[3] + tail;
}

extern "C" void kernel_launch(void* const* d_in, const int* in_sizes, int n_in,
                              void* d_out, int out_size, void* d_ws, size_t ws_size,
                              hipStream_t stream) {
    const int*   x     = (const int*)d_in[0];
    const float* W     = (const float*)d_in[1];
    const float* b_lut = (const float*)d_in[2];
    const float* bias  = (const float*)d_in[3];
    float*       out   = (float*)d_out;

    LR2_kernel<<<BATCH, 256, 0, stream>>>(x, W, b_lut, bias, out);
}